// Round 7
// baseline (1726.009 us; speedup 1.0000x reference)
//
#include <hip/hip_runtime.h>
#include <hip/hip_bf16.h>

#define NUM_C 1024
#define EMB   512
#define HID   512
#define BATCH 64
#define SEQ   512

typedef short bf16x8 __attribute__((ext_vector_type(8)));
typedef float f32x4  __attribute__((ext_vector_type(4)));

__device__ __forceinline__ unsigned short f2bf(float x) {
    unsigned u = __float_as_uint(x);
    u += 0x7fffu + ((u >> 16) & 1u);
    return (unsigned short)(u >> 16);
}
__device__ __forceinline__ float uaf(unsigned u) { return __uint_as_float(u); }

// fast tanh: exact at +-inf, ~1e-7 rel err, no branches
__device__ __forceinline__ float ftanh(float x) {
    float e = __expf(2.f * x);
    return 1.f - 2.f / (e + 1.f);
}

// ---------------------------------------------------------------------------
__global__ __launch_bounds__(256) void f32_to_bf16(const float* __restrict__ src,
                                                   unsigned short* __restrict__ dst, int n) {
    int i = blockIdx.x * 256 + threadIdx.x;
    if (i < n) dst[i] = f2bf(src[i]);
}

// ---------------------------------------------------------------------------
// fp32 vector GEMM (NT) for emb_proj = emb @ Wx^T + Wx_b + Wh_b
// ---------------------------------------------------------------------------
__global__ __launch_bounds__(256)
void gemm_nt_f32(const float* __restrict__ A, const float* __restrict__ B,
                 float* __restrict__ C, int M, int N, int K,
                 const float* __restrict__ bias1, const float* __restrict__ bias2) {
    __shared__ float As[64][33];
    __shared__ float Bs[64][33];

    const int n0 = blockIdx.x * 64;
    const int m0 = blockIdx.y * 64;
    const int tid = threadIdx.x;
    const int tx = tid & 15;
    const int ty = tid >> 4;

    float acc[4][4] = {{0.f}};

    for (int k0 = 0; k0 < K; k0 += 32) {
        #pragma unroll
        for (int i = 0; i < 2; ++i) {
            int f   = tid * 2 + i;
            int row = f >> 3;
            int kf  = f & 7;
            float4 va = *(const float4*)&A[(size_t)(m0 + row) * K + k0 + kf * 4];
            float4 vb = *(const float4*)&B[(size_t)(n0 + row) * K + k0 + kf * 4];
            As[row][kf * 4 + 0] = va.x; As[row][kf * 4 + 1] = va.y;
            As[row][kf * 4 + 2] = va.z; As[row][kf * 4 + 3] = va.w;
            Bs[row][kf * 4 + 0] = vb.x; Bs[row][kf * 4 + 1] = vb.y;
            Bs[row][kf * 4 + 2] = vb.z; Bs[row][kf * 4 + 3] = vb.w;
        }
        __syncthreads();
        #pragma unroll
        for (int kk = 0; kk < 32; ++kk) {
            float a[4], b[4];
            #pragma unroll
            for (int i = 0; i < 4; ++i) a[i] = As[ty * 4 + i][kk];
            #pragma unroll
            for (int j = 0; j < 4; ++j) b[j] = Bs[tx * 4 + j][kk];
            #pragma unroll
            for (int i = 0; i < 4; ++i)
                #pragma unroll
                for (int j = 0; j < 4; ++j)
                    acc[i][j] += a[i] * b[j];
        }
        __syncthreads();
    }

    float bb[4];
    #pragma unroll
    for (int j = 0; j < 4; ++j) {
        int n = n0 + tx * 4 + j;
        bb[j] = bias1[n] + bias2[n];
    }
    #pragma unroll
    for (int i = 0; i < 4; ++i) {
        size_t m = (size_t)(m0 + ty * 4 + i);
        float4 ov;
        ov.x = acc[i][0] + bb[0]; ov.y = acc[i][1] + bb[1];
        ov.z = acc[i][2] + bb[2]; ov.w = acc[i][3] + bb[3];
        *(float4*)&C[m * N + n0 + tx * 4] = ov;
    }
}

// ---------------------------------------------------------------------------
// LTC scan v7: v5 mechanics, deepened to 4 batch-rails per block.
// grid = 128 (sl = bid>>4 -> slice of 64 rows; g = bid&15 -> batches 4g..4g+3).
// W f32 in regs (64 VGPR).  4 phases per step, 1 barrier each:
//   P0: fin:finish3(s-1)+store | all:mac0(s) | pollers:poll1(s-1)
//   P1: fin:finish0(s)+store   | all:mac1(s) | pollers:poll2(s-1)
//   P2: fin:finish1(s)+store   | all:mac2(s) | pollers:poll3(s-1)
//   P3: fin:finish2(s)+store   | all:mac3(s) | pollers:poll0(s)
// Every store has ~2.5 phases in flight before partners poll it (stores first
// in phase, polls after the mac).  Exchange: sentinel 0x7F7F relaxed agent
// atomics (|h|<=1 -> halfword 0x7F7F unreachable); partner blocks stride 16
// -> same XCD.  Finish wave (w==sl) stores 32 contiguous words (coalesced).
// ---------------------------------------------------------------------------
#define FINISH(PS, E, H, HF, HSW, ST, NXT, ID)                                 \
    {                                                                          \
        float pre = E;                                                         \
        _Pragma("unroll")                                                      \
        for (int m = 0; m < 8; ++m) pre += PS[m * 64 + lane];                  \
        float hn = H + (ftanh(pre) - H) * rtau;                                \
        H = hn;                                                                \
        HF[sl * 64 + lane] = hn;                                               \
        unsigned us = f2bf(hn);                                                \
        unsigned ot = (unsigned)__shfl_xor((int)us, 1);                        \
        if (!(lane & 1))                                                       \
            __hip_atomic_store(&HSW[(ST) * 256 + sl * 32 + (lane >> 1)],       \
                               us | (ot << 16), __ATOMIC_RELAXED,              \
                               __HIP_MEMORY_SCOPE_AGENT);                      \
        if ((NXT) < SEQ)                                                       \
            E = emb_proj[(size_t)ID[NXT] * HID + sl * 64 + lane];              \
    }

#define MAC(HF, PS)                                                            \
    {                                                                          \
        const float4* h4 = (const float4*)(HF + w * 64);                       \
        float a0 = 0.f, a1 = 0.f, a2 = 0.f, a3 = 0.f;                          \
        _Pragma("unroll")                                                      \
        for (int i = 0; i < 16; ++i) {                                         \
            float4 hv = h4[i];                                                 \
            a0 += wr_[i].x * hv.x; a1 += wr_[i].y * hv.y;                      \
            a2 += wr_[i].z * hv.z; a3 += wr_[i].w * hv.w;                      \
        }                                                                      \
        PS[w * 64 + lane] = (a0 + a1) + (a2 + a3);                             \
    }

#define POLL(HSW, HF, ST)                                                      \
    if (lane < 32) {                                                           \
        unsigned* ap = &HSW[(ST) * 256 + w * 32 + lane];                       \
        unsigned word = __hip_atomic_load(ap, __ATOMIC_RELAXED,                \
                                          __HIP_MEMORY_SCOPE_AGENT);           \
        while ((word & 0xffffu) == 0x7f7fu)                                    \
            word = __hip_atomic_load(ap, __ATOMIC_RELAXED,                     \
                                     __HIP_MEMORY_SCOPE_AGENT);                \
        float2 hv; hv.x = uaf(word << 16); hv.y = uaf(word & 0xffff0000u);     \
        *(float2*)&HF[w * 64 + 2 * lane] = hv;                                 \
    }

__global__ __launch_bounds__(512, 2)
void ltc_scan7(const int* __restrict__ q, const int* __restrict__ r,
               const float* __restrict__ emb_proj, const float* __restrict__ Wh,
               const float* __restrict__ tau, unsigned short* __restrict__ hs_bf) {
    __shared__ float hf0[512], hf1[512], hf2[512], hf3[512];
    __shared__ float ps0[512], ps1[512], ps2[512], ps3[512];
    __shared__ int   id0[512], id1[512], id2[512], id3[512];

    const int tid  = threadIdx.x;
    const int sl   = blockIdx.x >> 4;     // slice: owns h rows sl*64..+63
    const int g    = blockIdx.x & 15;     // batch group: batches 4g..4g+3
    const int lane = tid & 63;
    const int w    = tid >> 6;            // wave = k-chunk = partner slice

    // W chunk -> regs: row sl*64+lane, cols w*64..+63 (fp32, 64 VGPR)
    float4 wr_[16];
    {
        const float* wrow = Wh + (size_t)(sl * 64 + lane) * 512 + w * 64;
        #pragma unroll
        for (int i = 0; i < 16; ++i) wr_[i] = ((const float4*)wrow)[i];
    }

    hf0[tid] = 0.f; hf1[tid] = 0.f; hf2[tid] = 0.f; hf3[tid] = 0.f;
    const int b0 = g * 4;
    id0[tid] = q[(b0 + 0) * SEQ + tid] + NUM_C * r[(b0 + 0) * SEQ + tid];
    id1[tid] = q[(b0 + 1) * SEQ + tid] + NUM_C * r[(b0 + 1) * SEQ + tid];
    id2[tid] = q[(b0 + 2) * SEQ + tid] + NUM_C * r[(b0 + 2) * SEQ + tid];
    id3[tid] = q[(b0 + 3) * SEQ + tid] + NUM_C * r[(b0 + 3) * SEQ + tid];

    const bool fin = (w == sl);
    float rtau = 0.f;
    float h0 = 0.f, h1 = 0.f, h2 = 0.f, h3 = 0.f;
    float e0 = 0.f, e1 = 0.f, e2 = 0.f, e3 = 0.f;
    if (fin) rtau = 1.0f / tau[sl * 64 + lane];

    unsigned* hsw0 = (unsigned*)(hs_bf + (size_t)(b0 + 0) * SEQ * HID);
    unsigned* hsw1 = (unsigned*)(hs_bf + (size_t)(b0 + 1) * SEQ * HID);
    unsigned* hsw2 = (unsigned*)(hs_bf + (size_t)(b0 + 2) * SEQ * HID);
    unsigned* hsw3 = (unsigned*)(hs_bf + (size_t)(b0 + 3) * SEQ * HID);
    __syncthreads();

    if (fin) {
        e0 = emb_proj[(size_t)id0[0] * HID + sl * 64 + lane];
        e1 = emb_proj[(size_t)id1[0] * HID + sl * 64 + lane];
        e2 = emb_proj[(size_t)id2[0] * HID + sl * 64 + lane];
        e3 = emb_proj[(size_t)id3[0] * HID + sl * 64 + lane];
    }

    for (int s = 0; s < SEQ; ++s) {
        // ---- P0: fin finish3(s-1) ; mac0(s) ; poll1(s-1) ----
        if (fin) { if (s > 0) FINISH(ps3, e3, h3, hf3, hsw3, s - 1, s, id3); }
        MAC(hf0, ps0);
        if (!fin && s > 0) POLL(hsw1, hf1, s - 1);
        __syncthreads();

        // ---- P1: fin finish0(s) ; mac1(s) ; poll2(s-1) ----
        if (fin) FINISH(ps0, e0, h0, hf0, hsw0, s, s + 1, id0);
        MAC(hf1, ps1);
        if (!fin && s > 0) POLL(hsw2, hf2, s - 1);
        __syncthreads();

        // ---- P2: fin finish1(s) ; mac2(s) ; poll3(s-1) ----
        if (fin) FINISH(ps1, e1, h1, hf1, hsw1, s, s + 1, id1);
        MAC(hf2, ps2);
        if (!fin && s > 0) POLL(hsw3, hf3, s - 1);
        __syncthreads();

        // ---- P3: fin finish2(s) ; mac3(s) ; poll0(s) ----
        if (fin) FINISH(ps2, e2, h2, hf2, hsw2, s, s + 1, id2);
        MAC(hf3, ps3);
        if (!fin && s + 1 < SEQ) POLL(hsw0, hf0, s);
        __syncthreads();
    }

    // epilogue: finish rail 3, step SEQ-1
    if (fin) FINISH(ps3, e3, h3, hf3, hsw3, SEQ - 1, SEQ, id3);
}

// ---------------------------------------------------------------------------
// Output GEMM: y = sigmoid(hs_bf @ Wo_bf^T + Wo_b), bf16 MFMA 16x16x32.
// ---------------------------------------------------------------------------
__global__ __launch_bounds__(256)
void gemm_out_bf16(const unsigned short* __restrict__ A,   // [M][512]
                   const unsigned short* __restrict__ B,   // [1024][512]
                   const float* __restrict__ bias,
                   float* __restrict__ C, int M) {
    __shared__ __align__(16) unsigned short As[128 * 32];
    __shared__ __align__(16) unsigned short Bs[128 * 32];

    const int tid = threadIdx.x;
    const int n0 = blockIdx.x * 128;
    const int m0 = blockIdx.y * 128;
    const int w  = tid >> 6;
    const int l  = tid & 63;
    const int wr = w >> 1, wc = w & 1;
    const int lr = l & 15;
    const int lq = l >> 4;

    f32x4 acc[4][4];
    #pragma unroll
    for (int i = 0; i < 4; ++i)
        #pragma unroll
        for (int jn = 0; jn < 4; ++jn)
            acc[i][jn] = (f32x4){0.f, 0.f, 0.f, 0.f};

    for (int k0 = 0; k0 < 512; k0 += 32) {
        #pragma unroll
        for (int p = 0; p < 2; ++p) {
            int flat = p * 256 + tid;
            int row  = flat >> 2;
            int c4   = flat & 3;
            *(uint4*)&As[row * 32 + c4 * 8] =
                *(const uint4*)&A[(size_t)(m0 + row) * 512 + k0 + c4 * 8];
            *(uint4*)&Bs[row * 32 + c4 * 8] =
                *(const uint4*)&B[(size_t)(n0 + row) * 512 + k0 + c4 * 8];
        }
        __syncthreads();

        bf16x8 af[4], bf[4];
        #pragma unroll
        for (int mf = 0; mf < 4; ++mf)
            af[mf] = *(const bf16x8*)&As[(wr * 64 + mf * 16 + lr) * 32 + lq * 8];
        #pragma unroll
        for (int nf = 0; nf < 4; ++nf)
            bf[nf] = *(const bf16x8*)&Bs[(wc * 64 + nf * 16 + lr) * 32 + lq * 8];

        #pragma unroll
        for (int mf = 0; mf < 4; ++mf)
            #pragma unroll
            for (int nf = 0; nf < 4; ++nf)
                acc[mf][nf] = __builtin_amdgcn_mfma_f32_16x16x32_bf16(
                    af[mf], bf[nf], acc[mf][nf], 0, 0, 0);
        __syncthreads();
    }

    #pragma unroll
    for (int mf = 0; mf < 4; ++mf) {
        #pragma unroll
        for (int nf = 0; nf < 4; ++nf) {
            int col = n0 + wc * 64 + nf * 16 + lr;
            float bb = bias[col];
            #pragma unroll
            for (int reg = 0; reg < 4; ++reg) {
                int rowm = m0 + wr * 64 + mf * 16 + lq * 4 + reg;
                float v = acc[mf][nf][reg] + bb;
                C[(size_t)rowm * 1024 + col] = 1.0f / (1.0f + expf(-v));
            }
        }
    }
}

// ---------------------------------------------------------------------------
extern "C" void kernel_launch(void* const* d_in, const int* in_sizes, int n_in,
                              void* d_out, int out_size, void* d_ws, size_t ws_size,
                              hipStream_t stream) {
    const int*   q    = (const int*)d_in[0];
    const int*   r    = (const int*)d_in[1];
    const float* emb  = (const float*)d_in[2];
    const float* Wh_w = (const float*)d_in[3];
    const float* Wh_b = (const float*)d_in[4];
    const float* Wx_w = (const float*)d_in[5];
    const float* Wx_b = (const float*)d_in[6];
    const float* tau  = (const float*)d_in[7];
    const float* Wo_w = (const float*)d_in[8];
    const float* Wo_b = (const float*)d_in[9];
    float* out = (float*)d_out;

    char* ws = (char*)d_ws;
    float*          emb_proj = (float*)ws;                                        // 4 MiB
    unsigned short* Wobf     = (unsigned short*)(ws + (4u << 20));                // 1 MiB
    unsigned short* hs_bf    = (unsigned short*)(ws + (5u << 20));                // 32 MiB

    // sentinel-fill hs (0x7F7F halfwords unreachable for |h|<=1 bf16)
    hipMemsetAsync(hs_bf, 0x7F, (size_t)BATCH * SEQ * HID * 2, stream);

    // Wo -> bf16 for the MFMA output GEMM
    f32_to_bf16<<<(1024 * 512) / 256, 256, 0, stream>>>(Wo_w, Wobf, 1024 * 512);

    // emb_proj = emb @ Wx^T + Wx_b + Wh_b (2048 distinct interaction rows)
    gemm_nt_f32<<<dim3(512 / 64, 2048 / 64), 256, 0, stream>>>(
        emb, Wx_w, emb_proj, 2048, 512, 512, Wx_b, Wh_b);

    // recurrence: 128 blocks (8 slices x 16 groups of 4 batches), 24KB LDS
    ltc_scan7<<<128, 512, 0, stream>>>(q, r, emb_proj, Wh_w, tau, hs_bf);

    // y = sigmoid(hs @ Wo^T + Wo_b) via bf16 MFMA
    gemm_out_bf16<<<dim3(1024 / 128, (BATCH * SEQ) / 128), 256, 0, stream>>>(
        hs_bf, Wobf, Wo_b, out, BATCH * SEQ);
}

// Round 8
// 873.888 us; speedup vs baseline: 1.9751x; 1.9751x over previous
//
#include <hip/hip_runtime.h>
#include <hip/hip_bf16.h>

#define NUM_C 1024
#define EMB   512
#define HID   512
#define BATCH 64
#define SEQ   512

typedef short bf16x8 __attribute__((ext_vector_type(8)));
typedef float f32x4  __attribute__((ext_vector_type(4)));

__device__ __forceinline__ unsigned short f2bf(float x) {
    unsigned u = __float_as_uint(x);
    u += 0x7fffu + ((u >> 16) & 1u);
    return (unsigned short)(u >> 16);
}
__device__ __forceinline__ float uaf(unsigned u) { return __uint_as_float(u); }

// fast tanh: exact at +-inf, ~1e-7 rel err, no branches
__device__ __forceinline__ float ftanh(float x) {
    float e = __expf(2.f * x);
    return 1.f - 2.f / (e + 1.f);
}

// ---------------------------------------------------------------------------
__global__ __launch_bounds__(256) void f32_to_bf16(const float* __restrict__ src,
                                                   unsigned short* __restrict__ dst, int n) {
    int i = blockIdx.x * 256 + threadIdx.x;
    if (i < n) dst[i] = f2bf(src[i]);
}

// ---------------------------------------------------------------------------
// fp32 vector GEMM (NT) for emb_proj = emb @ Wx^T + Wx_b + Wh_b
// ---------------------------------------------------------------------------
__global__ __launch_bounds__(256)
void gemm_nt_f32(const float* __restrict__ A, const float* __restrict__ B,
                 float* __restrict__ C, int M, int N, int K,
                 const float* __restrict__ bias1, const float* __restrict__ bias2) {
    __shared__ float As[64][33];
    __shared__ float Bs[64][33];

    const int n0 = blockIdx.x * 64;
    const int m0 = blockIdx.y * 64;
    const int tid = threadIdx.x;
    const int tx = tid & 15;
    const int ty = tid >> 4;

    float acc[4][4] = {{0.f}};

    for (int k0 = 0; k0 < K; k0 += 32) {
        #pragma unroll
        for (int i = 0; i < 2; ++i) {
            int f   = tid * 2 + i;
            int row = f >> 3;
            int kf  = f & 7;
            float4 va = *(const float4*)&A[(size_t)(m0 + row) * K + k0 + kf * 4];
            float4 vb = *(const float4*)&B[(size_t)(n0 + row) * K + k0 + kf * 4];
            As[row][kf * 4 + 0] = va.x; As[row][kf * 4 + 1] = va.y;
            As[row][kf * 4 + 2] = va.z; As[row][kf * 4 + 3] = va.w;
            Bs[row][kf * 4 + 0] = vb.x; Bs[row][kf * 4 + 1] = vb.y;
            Bs[row][kf * 4 + 2] = vb.z; Bs[row][kf * 4 + 3] = vb.w;
        }
        __syncthreads();
        #pragma unroll
        for (int kk = 0; kk < 32; ++kk) {
            float a[4], b[4];
            #pragma unroll
            for (int i = 0; i < 4; ++i) a[i] = As[ty * 4 + i][kk];
            #pragma unroll
            for (int j = 0; j < 4; ++j) b[j] = Bs[tx * 4 + j][kk];
            #pragma unroll
            for (int i = 0; i < 4; ++i)
                #pragma unroll
                for (int j = 0; j < 4; ++j)
                    acc[i][j] += a[i] * b[j];
        }
        __syncthreads();
    }

    float bb[4];
    #pragma unroll
    for (int j = 0; j < 4; ++j) {
        int n = n0 + tx * 4 + j;
        bb[j] = bias1[n] + bias2[n];
    }
    #pragma unroll
    for (int i = 0; i < 4; ++i) {
        size_t m = (size_t)(m0 + ty * 4 + i);
        float4 ov;
        ov.x = acc[i][0] + bb[0]; ov.y = acc[i][1] + bb[1];
        ov.z = acc[i][2] + bb[2]; ov.w = acc[i][3] + bb[3];
        *(float4*)&C[m * N + n0 + tx * 4] = ov;
    }
}

// ---------------------------------------------------------------------------
// LTC scan v8: h broadcast via readlane (NO LDS h), phase-top emb prefetch.
// v5 skeleton: 8 slices x 64 rows, W f32 in regs, 2 batch rails, grid=256
// (sl = bid>>5, bp = bid&31 -> batches 2bp,2bp+1; partners stride 32 = XCD).
//   P1: fin: [prefetch embB(s)] finishB(s-1)->pwB ; pollers: pollA(s-1)->pwA
//       all: macA(s) from pwA registers (readlane + fmac)          BAR
//   P2: fin: [prefetch embA(s+1)] finishA(s)->pwA ; pollers: pollB(s-1)->pwB
//       all: macB(s) from pwB                                       BAR
// pwX = 32 packed bf16 pairs in lanes 0..31 (one uint per lane); the mac
// broadcasts them with v_readlane (SALU unpack, fmac scalar operand) --
// zero LDS traffic in the h path.  Exchange: sentinel 0x7F7F relaxed agent
// atomics (|h|<=1 -> halfword 0x7F7F unreachable), coalesced fin-wave store.
// ---------------------------------------------------------------------------
#define PREFETCH(E_PF, ID, STEP)                                               \
    if (fin && (STEP) < SEQ)                                                   \
        E_PF = emb_proj[(size_t)ID[STEP] * HID + sl * 64 + lane];

#define FINISHX(PS, E, H, HSW, ST, PW)                                         \
    {                                                                          \
        float pre = E;                                                         \
        _Pragma("unroll")                                                      \
        for (int m = 0; m < 8; ++m) pre += PS[m * 64 + lane];                  \
        float hn = H + (ftanh(pre) - H) * rtau;                                \
        H = hn;                                                                \
        unsigned us = f2bf(hn);                                                \
        unsigned ot = (unsigned)__shfl_xor((int)us, 1);                        \
        unsigned word = us | (ot << 16);                                       \
        if (!(lane & 1))                                                       \
            __hip_atomic_store(&HSW[(ST) * 256 + sl * 32 + (lane >> 1)],       \
                               word, __ATOMIC_RELAXED,                         \
                               __HIP_MEMORY_SCOPE_AGENT);                      \
        PW = (unsigned)__shfl((int)word, (2 * lane) & 63);                     \
    }

#define POLLX(HSW, ST, PW)                                                     \
    {                                                                          \
        unsigned word = 0;                                                     \
        if (lane < 32) {                                                       \
            unsigned* ap = &HSW[(ST) * 256 + w * 32 + lane];                   \
            word = __hip_atomic_load(ap, __ATOMIC_RELAXED,                     \
                                     __HIP_MEMORY_SCOPE_AGENT);                \
            while ((word & 0xffffu) == 0x7f7fu) {                              \
                __builtin_amdgcn_s_sleep(1);                                   \
                word = __hip_atomic_load(ap, __ATOMIC_RELAXED,                 \
                                         __HIP_MEMORY_SCOPE_AGENT);            \
            }                                                                  \
        }                                                                      \
        PW = word;                                                             \
    }

#define MACX(PW, PS)                                                           \
    {                                                                          \
        float a0 = 0.f, a1 = 0.f, a2 = 0.f, a3 = 0.f;                          \
        _Pragma("unroll")                                                      \
        for (int t = 0; t < 32; t += 2) {                                      \
            unsigned w0 = (unsigned)__builtin_amdgcn_readlane((int)PW, t);     \
            unsigned w1 = (unsigned)__builtin_amdgcn_readlane((int)PW, t + 1); \
            a0 = fmaf(wf[2 * t],     uaf(w0 << 16),         a0);               \
            a1 = fmaf(wf[2 * t + 1], uaf(w0 & 0xffff0000u), a1);               \
            a2 = fmaf(wf[2 * t + 2], uaf(w1 << 16),         a2);               \
            a3 = fmaf(wf[2 * t + 3], uaf(w1 & 0xffff0000u), a3);               \
        }                                                                      \
        PS[w * 64 + lane] = (a0 + a1) + (a2 + a3);                             \
    }

__global__ __launch_bounds__(512, 2)
void ltc_scan8(const int* __restrict__ q, const int* __restrict__ r,
               const float* __restrict__ emb_proj, const float* __restrict__ Wh,
               const float* __restrict__ tau, unsigned short* __restrict__ hs_bf) {
    __shared__ float psA[512], psB[512];
    __shared__ int   idA[512], idB[512];

    const int tid  = threadIdx.x;
    const int sl   = blockIdx.x >> 5;     // slice: owns h rows sl*64..+63
    const int bp   = blockIdx.x & 31;
    const int bA   = bp * 2, bB = bA + 1;
    const int lane = tid & 63;
    const int w    = tid >> 6;            // wave = k-chunk = partner slice

    // W chunk -> regs: row sl*64+lane, cols w*64..+63 (fp32, 64 VGPR)
    float wf[64];
    {
        const float* wrow = Wh + (size_t)(sl * 64 + lane) * 512 + w * 64;
        #pragma unroll
        for (int i = 0; i < 16; ++i) {
            float4 v = ((const float4*)wrow)[i];
            wf[4 * i + 0] = v.x; wf[4 * i + 1] = v.y;
            wf[4 * i + 2] = v.z; wf[4 * i + 3] = v.w;
        }
    }

    idA[tid] = q[bA * SEQ + tid] + NUM_C * r[bA * SEQ + tid];
    idB[tid] = q[bB * SEQ + tid] + NUM_C * r[bB * SEQ + tid];

    const bool fin = (w == sl);
    float rtau = 0.f, hA = 0.f, hB = 0.f, eA = 0.f, eB = 0.f;
    unsigned pwA = 0, pwB = 0;            // packed h pairs, lanes 0..31
    if (fin) rtau = 1.0f / tau[sl * 64 + lane];

    unsigned* hswA = (unsigned*)(hs_bf + (size_t)bA * SEQ * HID);
    unsigned* hswB = (unsigned*)(hs_bf + (size_t)bB * SEQ * HID);
    __syncthreads();

    if (fin) eA = emb_proj[(size_t)idA[0] * HID + sl * 64 + lane];

    for (int s = 0; s < SEQ; ++s) {
        // ---- P1: fin prefetch embB(s), finishB(s-1) ; pollers pollA(s-1) ;
        //          all macA(s) ----
        float pfB = 0.f;
        PREFETCH(pfB, idB, s);
        if (fin) {
            if (s > 0) FINISHX(psB, eB, hB, hswB, s - 1, pwB);
            eB = pfB;
        } else if (s > 0) {
            POLLX(hswA, s - 1, pwA);
        }
        MACX(pwA, psA);
        __syncthreads();

        // ---- P2: fin prefetch embA(s+1), finishA(s) ; pollers pollB(s-1) ;
        //          all macB(s) ----
        float pfA = 0.f;
        PREFETCH(pfA, idA, s + 1);
        if (fin) {
            FINISHX(psA, eA, hA, hswA, s, pwA);
            eA = pfA;
        } else if (s > 0) {
            POLLX(hswB, s - 1, pwB);
        }
        MACX(pwB, psB);
        __syncthreads();
    }

    // epilogue: finishB(SEQ-1)
    if (fin) FINISHX(psB, eB, hB, hswB, SEQ - 1, pwB);
}

// ---------------------------------------------------------------------------
// Output GEMM: y = sigmoid(hs_bf @ Wo_bf^T + Wo_b), bf16 MFMA 16x16x32.
// ---------------------------------------------------------------------------
__global__ __launch_bounds__(256)
void gemm_out_bf16(const unsigned short* __restrict__ A,   // [M][512]
                   const unsigned short* __restrict__ B,   // [1024][512]
                   const float* __restrict__ bias,
                   float* __restrict__ C, int M) {
    __shared__ __align__(16) unsigned short As[128 * 32];
    __shared__ __align__(16) unsigned short Bs[128 * 32];

    const int tid = threadIdx.x;
    const int n0 = blockIdx.x * 128;
    const int m0 = blockIdx.y * 128;
    const int w  = tid >> 6;
    const int l  = tid & 63;
    const int wr = w >> 1, wc = w & 1;
    const int lr = l & 15;
    const int lq = l >> 4;

    f32x4 acc[4][4];
    #pragma unroll
    for (int i = 0; i < 4; ++i)
        #pragma unroll
        for (int jn = 0; jn < 4; ++jn)
            acc[i][jn] = (f32x4){0.f, 0.f, 0.f, 0.f};

    for (int k0 = 0; k0 < 512; k0 += 32) {
        #pragma unroll
        for (int p = 0; p < 2; ++p) {
            int flat = p * 256 + tid;
            int row  = flat >> 2;
            int c4   = flat & 3;
            *(uint4*)&As[row * 32 + c4 * 8] =
                *(const uint4*)&A[(size_t)(m0 + row) * 512 + k0 + c4 * 8];
            *(uint4*)&Bs[row * 32 + c4 * 8] =
                *(const uint4*)&B[(size_t)(n0 + row) * 512 + k0 + c4 * 8];
        }
        __syncthreads();

        bf16x8 af[4], bf[4];
        #pragma unroll
        for (int mf = 0; mf < 4; ++mf)
            af[mf] = *(const bf16x8*)&As[(wr * 64 + mf * 16 + lr) * 32 + lq * 8];
        #pragma unroll
        for (int nf = 0; nf < 4; ++nf)
            bf[nf] = *(const bf16x8*)&Bs[(wc * 64 + nf * 16 + lr) * 32 + lq * 8];

        #pragma unroll
        for (int mf = 0; mf < 4; ++mf)
            #pragma unroll
            for (int nf = 0; nf < 4; ++nf)
                acc[mf][nf] = __builtin_amdgcn_mfma_f32_16x16x32_bf16(
                    af[mf], bf[nf], acc[mf][nf], 0, 0, 0);
        __syncthreads();
    }

    #pragma unroll
    for (int mf = 0; mf < 4; ++mf) {
        #pragma unroll
        for (int nf = 0; nf < 4; ++nf) {
            int col = n0 + wc * 64 + nf * 16 + lr;
            float bb = bias[col];
            #pragma unroll
            for (int reg = 0; reg < 4; ++reg) {
                int rowm = m0 + wr * 64 + mf * 16 + lq * 4 + reg;
                float v = acc[mf][nf][reg] + bb;
                C[(size_t)rowm * 1024 + col] = 1.0f / (1.0f + expf(-v));
            }
        }
    }
}

// ---------------------------------------------------------------------------
extern "C" void kernel_launch(void* const* d_in, const int* in_sizes, int n_in,
                              void* d_out, int out_size, void* d_ws, size_t ws_size,
                              hipStream_t stream) {
    const int*   q    = (const int*)d_in[0];
    const int*   r    = (const int*)d_in[1];
    const float* emb  = (const float*)d_in[2];
    const float* Wh_w = (const float*)d_in[3];
    const float* Wh_b = (const float*)d_in[4];
    const float* Wx_w = (const float*)d_in[5];
    const float* Wx_b = (const float*)d_in[6];
    const float* tau  = (const float*)d_in[7];
    const float* Wo_w = (const float*)d_in[8];
    const float* Wo_b = (const float*)d_in[9];
    float* out = (float*)d_out;

    char* ws = (char*)d_ws;
    float*          emb_proj = (float*)ws;                                        // 4 MiB
    unsigned short* Wobf     = (unsigned short*)(ws + (4u << 20));                // 1 MiB
    unsigned short* hs_bf    = (unsigned short*)(ws + (5u << 20));                // 32 MiB

    // sentinel-fill hs (0x7F7F halfwords unreachable for |h|<=1 bf16)
    hipMemsetAsync(hs_bf, 0x7F, (size_t)BATCH * SEQ * HID * 2, stream);

    // Wo -> bf16 for the MFMA output GEMM
    f32_to_bf16<<<(1024 * 512) / 256, 256, 0, stream>>>(Wo_w, Wobf, 1024 * 512);

    // emb_proj = emb @ Wx^T + Wx_b + Wh_b (2048 distinct interaction rows)
    gemm_nt_f32<<<dim3(512 / 64, 2048 / 64), 256, 0, stream>>>(
        emb, Wx_w, emb_proj, 2048, 512, 512, Wx_b, Wh_b);

    // recurrence: 256 blocks (8 slices x 32 batch-pairs), 8KB LDS
    ltc_scan8<<<256, 512, 0, stream>>>(q, r, emb_proj, Wh_w, tau, hs_bf);

    // y = sigmoid(hs @ Wo^T + Wo_b) via bf16 MFMA
    gemm_out_bf16<<<dim3(1024 / 128, (BATCH * SEQ) / 128), 256, 0, stream>>>(
        hs_bf, Wobf, Wo_b, out, BATCH * SEQ);
}

// Round 9
// 801.178 us; speedup vs baseline: 2.1543x; 1.0908x over previous
//
#include <hip/hip_runtime.h>
#include <hip/hip_bf16.h>

#define NUM_C 1024
#define EMB   512
#define HID   512
#define BATCH 64
#define SEQ   512

typedef short bf16x8 __attribute__((ext_vector_type(8)));
typedef float f32x4  __attribute__((ext_vector_type(4)));

__device__ __forceinline__ unsigned short f2bf(float x) {
    unsigned u = __float_as_uint(x);
    u += 0x7fffu + ((u >> 16) & 1u);
    return (unsigned short)(u >> 16);
}
__device__ __forceinline__ unsigned pack2bf(float a, float b) {
    return (unsigned)f2bf(a) | ((unsigned)f2bf(b) << 16);
}
__device__ __forceinline__ float uaf(unsigned u) { return __uint_as_float(u); }

// fast tanh: exact at +-inf, ~1e-7 rel err, no branches
__device__ __forceinline__ float ftanh(float x) {
    float e = __expf(2.f * x);
    return 1.f - 2.f / (e + 1.f);
}

// ---------------------------------------------------------------------------
__global__ __launch_bounds__(256) void f32_to_bf16(const float* __restrict__ src,
                                                   unsigned short* __restrict__ dst, int n) {
    int i = blockIdx.x * 256 + threadIdx.x;
    if (i < n) dst[i] = f2bf(src[i]);
}

// ---------------------------------------------------------------------------
// fp32 vector GEMM (NT) for emb_proj = emb @ Wx^T + Wx_b + Wh_b
// ---------------------------------------------------------------------------
__global__ __launch_bounds__(256)
void gemm_nt_f32(const float* __restrict__ A, const float* __restrict__ B,
                 float* __restrict__ C, int M, int N, int K,
                 const float* __restrict__ bias1, const float* __restrict__ bias2) {
    __shared__ float As[64][33];
    __shared__ float Bs[64][33];

    const int n0 = blockIdx.x * 64;
    const int m0 = blockIdx.y * 64;
    const int tid = threadIdx.x;
    const int tx = tid & 15;
    const int ty = tid >> 4;

    float acc[4][4] = {{0.f}};

    for (int k0 = 0; k0 < K; k0 += 32) {
        #pragma unroll
        for (int i = 0; i < 2; ++i) {
            int f   = tid * 2 + i;
            int row = f >> 3;
            int kf  = f & 7;
            float4 va = *(const float4*)&A[(size_t)(m0 + row) * K + k0 + kf * 4];
            float4 vb = *(const float4*)&B[(size_t)(n0 + row) * K + k0 + kf * 4];
            As[row][kf * 4 + 0] = va.x; As[row][kf * 4 + 1] = va.y;
            As[row][kf * 4 + 2] = va.z; As[row][kf * 4 + 3] = va.w;
            Bs[row][kf * 4 + 0] = vb.x; Bs[row][kf * 4 + 1] = vb.y;
            Bs[row][kf * 4 + 2] = vb.z; Bs[row][kf * 4 + 3] = vb.w;
        }
        __syncthreads();
        #pragma unroll
        for (int kk = 0; kk < 32; ++kk) {
            float a[4], b[4];
            #pragma unroll
            for (int i = 0; i < 4; ++i) a[i] = As[ty * 4 + i][kk];
            #pragma unroll
            for (int j = 0; j < 4; ++j) b[j] = Bs[tx * 4 + j][kk];
            #pragma unroll
            for (int i = 0; i < 4; ++i)
                #pragma unroll
                for (int j = 0; j < 4; ++j)
                    acc[i][j] += a[i] * b[j];
        }
        __syncthreads();
    }

    float bb[4];
    #pragma unroll
    for (int j = 0; j < 4; ++j) {
        int n = n0 + tx * 4 + j;
        bb[j] = bias1[n] + bias2[n];
    }
    #pragma unroll
    for (int i = 0; i < 4; ++i) {
        size_t m = (size_t)(m0 + ty * 4 + i);
        float4 ov;
        ov.x = acc[i][0] + bb[0]; ov.y = acc[i][1] + bb[1];
        ov.z = acc[i][2] + bb[2]; ov.w = acc[i][3] + bb[3];
        *(float4*)&C[m * N + n0 + tx * 4] = ov;
    }
}

// ---------------------------------------------------------------------------
// LTC scan v9: one block per (slice,batch), free-running, 1 barrier/step.
// grid = 512 (sl = bid>>6, b = bid&63; partners stride 64 -> same XCD),
// 512 threads, 2 blocks/CU (launch_bounds(512,4), VGPR<=128, 6KB LDS) --
// the co-resident partner block (different batch) fills the CU during
// exchange waits via hardware TLP; no phase-locking between batches.
//   step s:  BAR | wave0: reduce ps + tanh -> h(s), store f32 to hx[s]
//                | all waves: poll hx[s] own 64-word k-chunk (f32, sentinel
//                  = NaN-exponent), readlane-broadcast mac -> ps_next
// h is exchanged in f32 (|h|<1 => exponent<=126; memset 0xFF gives exp=255
// sentinel), so there is NO pack/unpack anywhere in the critical path and
// the recurrence is exact f32.  hx doubles as the A operand of the output
// GEMM (converted to bf16 during GEMM LDS staging, off the critical path).
// ---------------------------------------------------------------------------
#define STEP9(PS_CUR, PS_NXT, S)                                               \
    __syncthreads();                                                           \
    if (fin) {                                                                 \
        float pre = e;                                                         \
        _Pragma("unroll")                                                      \
        for (int m = 0; m < 8; ++m) pre += PS_CUR[m * 64 + lane];              \
        float hn = h + (ftanh(pre) - h) * rtau;                                \
        h = hn;                                                                \
        __hip_atomic_store((unsigned*)&hxb[(S) * 512 + sl * 64 + lane],        \
                           __float_as_uint(hn), __ATOMIC_RELAXED,              \
                           __HIP_MEMORY_SCOPE_AGENT);                          \
        if ((S) + 1 < SEQ)                                                     \
            e = emb_proj[(size_t)ids[(S) + 1] * HID + sl * 64 + lane];         \
    }                                                                          \
    if ((S) + 1 < SEQ) {                                                       \
        unsigned* ap = (unsigned*)&hxb[(S) * 512 + w * 64 + lane];             \
        int wi = (int)__hip_atomic_load(ap, __ATOMIC_RELAXED,                  \
                                        __HIP_MEMORY_SCOPE_AGENT);             \
        while (((unsigned)wi & 0x7f800000u) == 0x7f800000u) {                  \
            __builtin_amdgcn_s_sleep(1);                                       \
            wi = (int)__hip_atomic_load(ap, __ATOMIC_RELAXED,                  \
                                        __HIP_MEMORY_SCOPE_AGENT);             \
        }                                                                      \
        float a0 = 0.f, a1 = 0.f, a2 = 0.f, a3 = 0.f;                          \
        _Pragma("unroll")                                                      \
        for (int t = 0; t < 64; t += 4) {                                      \
            a0 = fmaf(wf[t + 0],                                               \
                      uaf((unsigned)__builtin_amdgcn_readlane(wi, t + 0)), a0);\
            a1 = fmaf(wf[t + 1],                                               \
                      uaf((unsigned)__builtin_amdgcn_readlane(wi, t + 1)), a1);\
            a2 = fmaf(wf[t + 2],                                               \
                      uaf((unsigned)__builtin_amdgcn_readlane(wi, t + 2)), a2);\
            a3 = fmaf(wf[t + 3],                                               \
                      uaf((unsigned)__builtin_amdgcn_readlane(wi, t + 3)), a3);\
        }                                                                      \
        PS_NXT[w * 64 + lane] = (a0 + a1) + (a2 + a3);                         \
    }

__global__ __launch_bounds__(512, 4)
void ltc_scan9(const int* __restrict__ q, const int* __restrict__ r,
               const float* __restrict__ emb_proj, const float* __restrict__ Wh,
               const float* __restrict__ tau, float* __restrict__ hx) {
    __shared__ float psA[512], psB[512];
    __shared__ int   ids[512];

    const int tid  = threadIdx.x;
    const int sl   = blockIdx.x >> 6;     // slice: owns h rows sl*64..+63
    const int b    = blockIdx.x & 63;     // batch
    const int lane = tid & 63;
    const int w    = tid >> 6;            // wave = k-chunk = source slice

    // W chunk -> regs: row sl*64+lane, cols w*64..+63 (fp32, 64 VGPR)
    float wf[64];
    {
        const float* wrow = Wh + (size_t)(sl * 64 + lane) * 512 + w * 64;
        #pragma unroll
        for (int i = 0; i < 16; ++i) {
            float4 v = ((const float4*)wrow)[i];
            wf[4 * i + 0] = v.x; wf[4 * i + 1] = v.y;
            wf[4 * i + 2] = v.z; wf[4 * i + 3] = v.w;
        }
    }

    ids[tid] = q[b * SEQ + tid] + NUM_C * r[b * SEQ + tid];
    psA[tid] = 0.f;                        // partials for step 0 (h(-1)=0)

    const bool fin = (w == 0);             // wave 0 finishes all 64 rows
    float rtau = 0.f, h = 0.f, e = 0.f;
    if (fin) rtau = 1.0f / tau[sl * 64 + lane];

    float* hxb = hx + (size_t)b * SEQ * HID;
    __syncthreads();                       // ids, psA ready

    if (fin) e = emb_proj[(size_t)ids[0] * HID + sl * 64 + lane];

    for (int s = 0; s < SEQ; s += 2) {
        STEP9(psA, psB, s);
        STEP9(psB, psA, s + 1);
    }
}

// ---------------------------------------------------------------------------
// Output GEMM: y = sigmoid(A_f32 @ Wo_bf^T + Wo_b), bf16 MFMA 16x16x32.
// A is read in f32 (the scan's hx buffer) and converted to bf16 during LDS
// staging; B (Wo) is pre-converted bf16.
// ---------------------------------------------------------------------------
__global__ __launch_bounds__(256)
void gemm_out_bf16(const float* __restrict__ A,             // [M][512] f32
                   const unsigned short* __restrict__ B,    // [1024][512] bf16
                   const float* __restrict__ bias,
                   float* __restrict__ C, int M) {
    __shared__ __align__(16) unsigned short As[128 * 32];
    __shared__ __align__(16) unsigned short Bs[128 * 32];

    const int tid = threadIdx.x;
    const int n0 = blockIdx.x * 128;
    const int m0 = blockIdx.y * 128;
    const int w  = tid >> 6;
    const int l  = tid & 63;
    const int wr = w >> 1, wc = w & 1;
    const int lr = l & 15;
    const int lq = l >> 4;

    f32x4 acc[4][4];
    #pragma unroll
    for (int i = 0; i < 4; ++i)
        #pragma unroll
        for (int jn = 0; jn < 4; ++jn)
            acc[i][jn] = (f32x4){0.f, 0.f, 0.f, 0.f};

    for (int k0 = 0; k0 < 512; k0 += 32) {
        #pragma unroll
        for (int p = 0; p < 2; ++p) {
            int flat = p * 256 + tid;
            int row  = flat >> 2;
            int c4   = flat & 3;
            const float* asrc = &A[(size_t)(m0 + row) * 512 + k0 + c4 * 8];
            float4 v0 = ((const float4*)asrc)[0];
            float4 v1 = ((const float4*)asrc)[1];
            uint4 d;
            d.x = pack2bf(v0.x, v0.y); d.y = pack2bf(v0.z, v0.w);
            d.z = pack2bf(v1.x, v1.y); d.w = pack2bf(v1.z, v1.w);
            *(uint4*)&As[row * 32 + c4 * 8] = d;
            *(uint4*)&Bs[row * 32 + c4 * 8] =
                *(const uint4*)&B[(size_t)(n0 + row) * 512 + k0 + c4 * 8];
        }
        __syncthreads();

        bf16x8 af[4], bf[4];
        #pragma unroll
        for (int mf = 0; mf < 4; ++mf)
            af[mf] = *(const bf16x8*)&As[(wr * 64 + mf * 16 + lr) * 32 + lq * 8];
        #pragma unroll
        for (int nf = 0; nf < 4; ++nf)
            bf[nf] = *(const bf16x8*)&Bs[(wc * 64 + nf * 16 + lr) * 32 + lq * 8];

        #pragma unroll
        for (int mf = 0; mf < 4; ++mf)
            #pragma unroll
            for (int nf = 0; nf < 4; ++nf)
                acc[mf][nf] = __builtin_amdgcn_mfma_f32_16x16x32_bf16(
                    af[mf], bf[nf], acc[mf][nf], 0, 0, 0);
        __syncthreads();
    }

    #pragma unroll
    for (int mf = 0; mf < 4; ++mf) {
        #pragma unroll
        for (int nf = 0; nf < 4; ++nf) {
            int col = n0 + wc * 64 + nf * 16 + lr;
            float bb = bias[col];
            #pragma unroll
            for (int reg = 0; reg < 4; ++reg) {
                int rowm = m0 + wr * 64 + mf * 16 + lq * 4 + reg;
                float v = acc[mf][nf][reg] + bb;
                C[(size_t)rowm * 1024 + col] = 1.0f / (1.0f + expf(-v));
            }
        }
    }
}

// ---------------------------------------------------------------------------
extern "C" void kernel_launch(void* const* d_in, const int* in_sizes, int n_in,
                              void* d_out, int out_size, void* d_ws, size_t ws_size,
                              hipStream_t stream) {
    const int*   q    = (const int*)d_in[0];
    const int*   r    = (const int*)d_in[1];
    const float* emb  = (const float*)d_in[2];
    const float* Wh_w = (const float*)d_in[3];
    const float* Wh_b = (const float*)d_in[4];
    const float* Wx_w = (const float*)d_in[5];
    const float* Wx_b = (const float*)d_in[6];
    const float* tau  = (const float*)d_in[7];
    const float* Wo_w = (const float*)d_in[8];
    const float* Wo_b = (const float*)d_in[9];
    float* out = (float*)d_out;

    char* ws = (char*)d_ws;
    float*          emb_proj = (float*)ws;                           // 4 MiB
    unsigned short* Wobf     = (unsigned short*)(ws + (4u << 20));   // 1 MiB
    float*          hx       = (float*)(ws + (5u << 20));            // 64 MiB f32

    // sentinel-fill hx: 0xFF bytes -> exponent 255 (NaN); legit |h|<1 has
    // exponent <= 126, so any stored h clears the sentinel test.
    hipMemsetAsync(hx, 0xFF, (size_t)BATCH * SEQ * HID * 4, stream);

    // Wo -> bf16 for the MFMA output GEMM
    f32_to_bf16<<<(1024 * 512) / 256, 256, 0, stream>>>(Wo_w, Wobf, 1024 * 512);

    // emb_proj = emb @ Wx^T + Wx_b + Wh_b (2048 distinct interaction rows)
    gemm_nt_f32<<<dim3(512 / 64, 2048 / 64), 256, 0, stream>>>(
        emb, Wx_w, emb_proj, 2048, 512, 512, Wx_b, Wh_b);

    // recurrence: 512 blocks (8 slices x 64 batches), 2 blocks/CU, 6KB LDS
    ltc_scan9<<<512, 512, 0, stream>>>(q, r, emb_proj, Wh_w, tau, hx);

    // y = sigmoid(hx @ Wo^T + Wo_b) via bf16 MFMA (A staged f32 -> bf16)
    gemm_out_bf16<<<dim3(1024 / 128, (BATCH * SEQ) / 128), 256, 0, stream>>>(
        hx, Wobf, Wo_b, out, BATCH * SEQ);
}